// Round 4
// baseline (494.124 us; speedup 1.0000x reference)
//
#include <hip/hip_runtime.h>
#include <hip/hip_cooperative_groups.h>

namespace cg = cooperative_groups;

// GCN imputation (C=1), fused single cooperative kernel (grid=512, 2 blk/CU —
// conservative co-residency so hipLaunchCooperativeKernel cannot be rejected
// for occupancy). Fallback multi-kernel chain if coop launch errors (R3 failed
// with d_out untouched => launch was rejected, likely TooLarge at 1024 blocks).
//
//   a[d,g]  = sum_e norm_e * xt[s,g] + dinv[d]^2 * xt[d,g]
//   z       = sum_f relu(W1[f]*a+b1[f])*W2[f]
//   o[d,g]  = sum_e norm_e * z[s,g] + dinv[d]^2 * z[d,g] + b2
//   out     = mask ? x : o
// Node-major (n*64+g) layout: one wave per edge/node, 256B coalesced.

#define G 64

// ============================ fused cooperative ============================
__global__ void __launch_bounds__(256, 2)
stgi_fused(const float* __restrict__ x,
           const int*   __restrict__ mask,
           const int*   __restrict__ src,
           const int*   __restrict__ dst,
           const float* __restrict__ ew,
           const float* __restrict__ W1,
           const float* __restrict__ b1,
           const float* __restrict__ W2,
           const float* __restrict__ b2,
           float* __restrict__ out,
           float* __restrict__ deg,    // N (pre-zeroed by memset)
           float* __restrict__ dinv,   // N
           float* __restrict__ xt,     // N*G
           float* __restrict__ a,      // N*G
           float* __restrict__ z,      // N*G
           float* __restrict__ o,      // N*G
           int N, int E) {
    cg::grid_group grid = cg::this_grid();
    const int tid    = blockIdx.x * blockDim.x + threadIdx.x;
    const int nth    = gridDim.x * blockDim.x;
    const int lane   = threadIdx.x & 63;
    const int wquad  = threadIdx.x >> 6;
    const int gwave  = tid >> 6;
    const int nwaves = nth >> 6;

    __shared__ float tile[64][65];

    // ---- P1: deg[d] += w ----
    for (int e = tid; e < E; e += nth) atomicAdd(&deg[dst[e]], ew[e]);
    grid.sync();

    // ---- P2: tiled transpose x->xt; dinv; self-loop seed a = dinv^2*x ----
    const int ntiles = (N + 63) / 64;
    for (int t = blockIdx.x; t < ntiles; t += gridDim.x) {
        int n0 = t * 64;
#pragma unroll
        for (int i = 0; i < 16; ++i) {
            int g = wquad + i * 4;
            int n = n0 + lane;
            if (n < N) tile[g][lane] = x[g * N + n];      // coalesced read
        }
        __syncthreads();
#pragma unroll
        for (int i = 0; i < 16; ++i) {
            int nl = wquad + i * 4;
            int n = n0 + nl;
            if (n < N) {
                float di = rsqrtf(deg[n] + 1.0f);         // +1 = self-loop wt
                float v = tile[lane][nl];                 // stride-65
                xt[n * G + lane] = v;
                a[n * G + lane] = di * di * v;
                if (lane == 0) dinv[n] = di;
            }
        }
        __syncthreads();
    }
    grid.sync();

    // ---- P3: edge pass 1 — a[d,g] += dinv[s]*w*dinv[d]*xt[s,g] ----
    for (int e = gwave; e < E; e += nwaves) {
        int s = src[e], d = dst[e];
        float nrm = dinv[s] * ew[e] * dinv[d];
        atomicAdd(&a[d * G + lane], nrm * xt[s * G + lane]);
    }
    grid.sync();

    // ---- P4: z = phi(a); o seed = b2 + dinv^2*z ----
    {
        float b2v = b2[0];
        for (int t = tid; t < N * G; t += nth) {
            int n = t >> 6;
            float av = a[t];
            float zv = 0.0f;
#pragma unroll
            for (int f = 0; f < 32; ++f)
                zv = fmaf(fmaxf(fmaf(W1[f], av, b1[f]), 0.0f), W2[f], zv);
            z[t] = zv;
            float di = dinv[n];
            o[t] = fmaf(di * di, zv, b2v);
        }
    }
    grid.sync();

    // ---- P5: edge pass 2 — o[d,g] += norm * z[s,g] ----
    for (int e = gwave; e < E; e += nwaves) {
        int s = src[e], d = dst[e];
        float nrm = dinv[s] * ew[e] * dinv[d];
        atomicAdd(&o[d * G + lane], nrm * z[s * G + lane]);
    }
    grid.sync();

    // ---- P6: finalize — out[g*N+n] = mask ? x : o[n,g] ----
    for (int t = blockIdx.x; t < ntiles; t += gridDim.x) {
        int n0 = t * 64;
#pragma unroll
        for (int i = 0; i < 16; ++i) {
            int nl = wquad + i * 4;
            int n = n0 + nl;
            if (n < N) tile[nl][lane] = o[n * G + lane];
        }
        __syncthreads();
#pragma unroll
        for (int i = 0; i < 16; ++i) {
            int g = wquad + i * 4;
            int n = n0 + lane;
            if (n < N) {
                int idx = g * N + n;
                out[idx] = mask[idx] ? x[idx] : tile[lane][g];
            }
        }
        __syncthreads();
    }
}

// ============================ fallback chain ============================
__global__ void fb_deg(const int* __restrict__ dst, const float* __restrict__ w,
                       float* __restrict__ deg, int E) {
    int e = blockIdx.x * blockDim.x + threadIdx.x;
    if (e < E) atomicAdd(&deg[dst[e]], w[e]);
}

__global__ void fb_tinit(const float* __restrict__ x, const float* __restrict__ deg,
                         float* __restrict__ dinv, float* __restrict__ xt,
                         float* __restrict__ a, int N) {
    __shared__ float tile[64][65];
    int n0 = blockIdx.x * 64;
    int lane = threadIdx.x & 63, wquad = threadIdx.x >> 6;
#pragma unroll
    for (int i = 0; i < 16; ++i) {
        int g = wquad + i * 4, n = n0 + lane;
        if (n < N) tile[g][lane] = x[g * N + n];
    }
    __syncthreads();
#pragma unroll
    for (int i = 0; i < 16; ++i) {
        int nl = wquad + i * 4, n = n0 + nl;
        if (n < N) {
            float di = rsqrtf(deg[n] + 1.0f);
            float v = tile[lane][nl];
            xt[n * G + lane] = v;
            a[n * G + lane] = di * di * v;
            if (lane == 0) dinv[n] = di;
        }
    }
}

__global__ void fb_edge(const int* __restrict__ src, const int* __restrict__ dst,
                        const float* __restrict__ w, const float* __restrict__ dinv,
                        const float* __restrict__ inv, float* __restrict__ outv, int E) {
    int wid = (blockIdx.x * blockDim.x + threadIdx.x) >> 6;
    int lane = threadIdx.x & 63;
    if (wid >= E) return;
    int s = src[wid], d = dst[wid];
    float nrm = dinv[s] * w[wid] * dinv[d];
    atomicAdd(&outv[d * G + lane], nrm * inv[s * G + lane]);
}

__global__ void fb_phi(const float* __restrict__ a, const float* __restrict__ dinv,
                       const float* __restrict__ W1, const float* __restrict__ b1,
                       const float* __restrict__ W2, const float* __restrict__ b2,
                       float* __restrict__ z, float* __restrict__ o, int total) {
    int t = blockIdx.x * blockDim.x + threadIdx.x;
    if (t >= total) return;
    int n = t >> 6;
    float av = a[t];
    float zv = 0.0f;
#pragma unroll
    for (int f = 0; f < 32; ++f)
        zv = fmaf(fmaxf(fmaf(W1[f], av, b1[f]), 0.0f), W2[f], zv);
    z[t] = zv;
    float di = dinv[n];
    o[t] = fmaf(di * di, zv, b2[0]);
}

__global__ void fb_fin(const float* __restrict__ x, const int* __restrict__ mask,
                       const float* __restrict__ o, float* __restrict__ out, int N) {
    __shared__ float tile[64][65];
    int n0 = blockIdx.x * 64;
    int lane = threadIdx.x & 63, wquad = threadIdx.x >> 6;
#pragma unroll
    for (int i = 0; i < 16; ++i) {
        int nl = wquad + i * 4, n = n0 + nl;
        if (n < N) tile[nl][lane] = o[n * G + lane];
    }
    __syncthreads();
#pragma unroll
    for (int i = 0; i < 16; ++i) {
        int g = wquad + i * 4, n = n0 + lane;
        if (n < N) {
            int idx = g * N + n;
            out[idx] = mask[idx] ? x[idx] : tile[lane][g];
        }
    }
}

extern "C" void kernel_launch(void* const* d_in, const int* in_sizes, int n_in,
                              void* d_out, int out_size, void* d_ws, size_t ws_size,
                              hipStream_t stream) {
    const float* x    = (const float*)d_in[0];
    const int*   mask = (const int*)  d_in[1];
    const int*   eidx = (const int*)  d_in[2];
    const float* ew   = (const float*)d_in[3];
    const float* W1   = (const float*)d_in[4];
    const float* b1   = (const float*)d_in[5];
    const float* W2   = (const float*)d_in[6];
    const float* b2   = (const float*)d_in[7];
    float* out = (float*)d_out;

    int E = in_sizes[3];        // 160000
    int N = in_sizes[0] / G;    // 10000
    const int total = N * G;

    const int* src = eidx;
    const int* dst = eidx + E;

    float* ws   = (float*)d_ws;
    float* deg  = ws;                 // N
    float* dinv = ws + 16384;         // N
    float* xt   = ws + 32768;         // total
    float* a    = xt + total;         // total
    float* z    = a + total;          // total
    float* o    = z + total;          // total

    hipMemsetAsync(deg, 0, N * sizeof(float), stream);

    void* args[] = {
        (void*)&x, (void*)&mask, (void*)&src, (void*)&dst, (void*)&ew,
        (void*)&W1, (void*)&b1, (void*)&W2, (void*)&b2, (void*)&out,
        (void*)&deg, (void*)&dinv, (void*)&xt, (void*)&a, (void*)&z, (void*)&o,
        (void*)&N, (void*)&E
    };
    hipError_t err = hipLaunchCooperativeKernel((const void*)stgi_fused,
                                                dim3(512), dim3(256), args, 0, stream);
    if (err != hipSuccess) {
        // deterministic fallback: same math, 6 chained dispatches
        fb_deg  <<<(E + 255) / 256, 256, 0, stream>>>(dst, ew, deg, E);
        fb_tinit<<<(N + 63) / 64, 256, 0, stream>>>(x, deg, dinv, xt, a, N);
        fb_edge <<<(E + 3) / 4, 256, 0, stream>>>(src, dst, ew, dinv, xt, a, E);
        fb_phi  <<<(total + 255) / 256, 256, 0, stream>>>(a, dinv, W1, b1, W2, b2, z, o, total);
        fb_edge <<<(E + 3) / 4, 256, 0, stream>>>(src, dst, ew, dinv, z, o, E);
        fb_fin  <<<(N + 63) / 64, 256, 0, stream>>>(x, mask, o, out, N);
    }
}